// Round 5
// baseline (1172.608 us; speedup 1.0000x reference)
//
#include <hip/hip_runtime.h>
#include <hip/hip_bf16.h>

#define NB   16       // batches
#define NN   10000    // nodes per batch
#define NE   160000   // edges per batch
#define NODES (NB*NN) // 160000 total nodes
#define IN_F 19
#define HF   64
#define OUTF 32
#define LN_EPS 1e-5f
#define RANGE 625     // dst nodes owned per block in count/fill (16 blocks/batch)

// R5 structure notes:
// * CSR build: R1-R4 edge-parallel scatter wrote 117MB HBM for 10.2MB of CSR
//   (same-line stores from different XCDs can't merge in non-coherent L2s).
//   Fix is structural ownership: block = (batch, 625-node dst range) streams
//   the batch's dst array, LDS-counts / LDS-cursors its range, and writes its
//   own contiguous ~40KB CSR segment -> full-line writebacks, no global
//   atomics, no cursor, no memset.
// * agg gathers are the biggest cache-traffic term (2.56M x 256B rows/layer).
//   Keep fp32 x for dense math + residual, maintain a bf16 shadow xh for
//   gathers and a bf16 agg array -> gather bytes halve. RN packing keeps
//   error ~0.4% << 2% threshold.
// * Dense kernels: chunk k by 8, constant-indexed av[8], wave-uniform weight
//   rows -> s_load + v_fmac(SGPR); no LDS, no spills (R2-R4 lessons).

__device__ inline unsigned pk_bf16(float a, float b) {
    __hip_bfloat162 h = __float22bfloat162_rn(float2{a, b});
    return *(unsigned*)&h;
}

// ---------------- enc1: h = relu(nf@W1+b1), fully unrolled (k=19 const) ----------------
__global__ __launch_bounds__(256) void enc1_kernel(
    const float* __restrict__ nf,
    const float* __restrict__ w1, const float* __restrict__ b1,
    float* __restrict__ x)
{
    int node = blockIdx.x * 256 + threadIdx.x;   // 625*256 = 160000 exactly
    const float* p = nf + (size_t)node * IN_F;
    float a[IN_F];
#pragma unroll
    for (int k = 0; k < IN_F; ++k) a[k] = p[k];

    float h[HF];
#pragma unroll
    for (int j = 0; j < HF; ++j) h[j] = b1[j];
#pragma unroll
    for (int k = 0; k < IN_F; ++k) {
        float ak = a[k];
        const float* wr = w1 + k * HF;           // wave-uniform -> s_load
#pragma unroll
        for (int j = 0; j < HF; ++j) h[j] = fmaf(ak, wr[j], h[j]);
    }

    float4* dst = (float4*)(x + (size_t)node * HF);
#pragma unroll
    for (int q = 0; q < 16; ++q) {
        float4 v;
        v.x = fmaxf(h[4*q],   0.f); v.y = fmaxf(h[4*q+1], 0.f);
        v.z = fmaxf(h[4*q+2], 0.f); v.w = fmaxf(h[4*q+3], 0.f);
        dst[q] = v;
    }
}

// ---------------- gemm64: x = x @ W + b in-place; also writes bf16 shadow xh ----------------
__global__ __launch_bounds__(256) void gemm64_kernel(
    float* __restrict__ x, const float* __restrict__ W, const float* __restrict__ bias,
    __hip_bfloat16* __restrict__ xh)
{
    int node = blockIdx.x * 256 + threadIdx.x;
    const float* row = x + (size_t)node * HF;

    float acc[HF];
#pragma unroll
    for (int j = 0; j < HF; ++j) acc[j] = bias[j];

#pragma unroll 1
    for (int kc = 0; kc < HF; kc += 8) {
        float4 v0 = *(const float4*)(row + kc);
        float4 v1 = *(const float4*)(row + kc + 4);
        float av[8] = {v0.x, v0.y, v0.z, v0.w, v1.x, v1.y, v1.z, v1.w};
#pragma unroll
        for (int u = 0; u < 8; ++u) {
            const float* wr = W + (kc + u) * HF;
#pragma unroll
            for (int j = 0; j < HF; ++j) acc[j] = fmaf(av[u], wr[j], acc[j]);
        }
    }

    float4* dst = (float4*)(x + (size_t)node * HF);
#pragma unroll
    for (int q = 0; q < 16; ++q) {
        float4 v; v.x = acc[4*q]; v.y = acc[4*q+1]; v.z = acc[4*q+2]; v.w = acc[4*q+3];
        dst[q] = v;
    }
    uint4* hdst = (uint4*)(xh + (size_t)node * HF);
#pragma unroll
    for (int q = 0; q < 8; ++q) {
        uint4 u;
        u.x = pk_bf16(acc[8*q+0], acc[8*q+1]);
        u.y = pk_bf16(acc[8*q+2], acc[8*q+3]);
        u.z = pk_bf16(acc[8*q+4], acc[8*q+5]);
        u.w = pk_bf16(acc[8*q+6], acc[8*q+7]);
        hdst[q] = u;
    }
}

// ---------------- count: block owns (batch, dst range); LDS histogram ----------------
__global__ __launch_bounds__(256) void count_kernel(const int* __restrict__ ei,
                                                    int* __restrict__ cnt)
{
    __shared__ int lcnt[RANGE];
    int b  = blockIdx.x >> 4;                    // 16 batches
    int lo = (blockIdx.x & 15) * RANGE;          // 16 ranges * 625 = 10000
    int t  = threadIdx.x;
    for (int i = t; i < RANGE; i += 256) lcnt[i] = 0;
    __syncthreads();

    const int* dstp = ei + (size_t)b * 2 * NE + NE;
    for (int e = t; e < NE; e += 256) {          // 625 coalesced sweeps
        unsigned ld = (unsigned)(dstp[e] - lo);
        if (ld < RANGE) atomicAdd(&lcnt[ld], 1);
    }
    __syncthreads();
    for (int i = t; i < RANGE; i += 256) cnt[b * NN + lo + i] = lcnt[i];
}

// ---------------- scan: per-batch exclusive prefix over cnt ----------------
__global__ __launch_bounds__(256) void scan_kernel(const int* __restrict__ cnt, int* __restrict__ off)
{
    __shared__ int sdata[256];
    int b = blockIdx.x, t = threadIdx.x;
    const int CH = 40;                          // 256*40 = 10240 >= NN
    int lo = t * CH, hi = min(lo + CH, NN);
    int s = 0;
    for (int i = lo; i < hi; ++i) s += cnt[b * NN + i];
    sdata[t] = s;
    __syncthreads();
    for (int ofs = 1; ofs < 256; ofs <<= 1) {
        int v = (t >= ofs) ? sdata[t - ofs] : 0;
        __syncthreads();
        sdata[t] += v;
        __syncthreads();
    }
    int run = (t > 0) ? sdata[t - 1] : 0;       // exclusive prefix
    for (int i = lo; i < hi; ++i) { off[b * NN + i] = run; run += cnt[b * NN + i]; }
}

// ---------------- fillb: block-owned CSR segment fill, LDS cursors ----------------
__global__ __launch_bounds__(256) void fillb_kernel(const int* __restrict__ ei,
                                                    const int* __restrict__ off,
                                                    int* __restrict__ csr)
{
    __shared__ int lcur[RANGE];
    int b  = blockIdx.x >> 4;
    int lo = (blockIdx.x & 15) * RANGE;
    int t  = threadIdx.x;
    for (int i = t; i < RANGE; i += 256) lcur[i] = 0;
    __syncthreads();

    const int* eb = ei + (size_t)b * 2 * NE;
    const int* offb = off + b * NN;
    int* csrb = csr + (size_t)b * NE;
    for (int e = t; e < NE; e += 256) {
        int d = eb[NE + e];
        unsigned ld = (unsigned)(d - lo);
        if (ld < RANGE) {
            int s = eb[e];                       // exec-masked load
            int pos = offb[d] + atomicAdd(&lcur[ld], 1);
            csrb[pos] = s;                       // block-exclusive ~40KB segment
        }
    }
}

// ---------------- mean aggregation: wave per node, lane per channel, bf16 gathers ----------------
__global__ __launch_bounds__(256) void agg_kernel(const __hip_bfloat16* __restrict__ xh,
                                                  const int* __restrict__ cnt,
                                                  const int* __restrict__ off,
                                                  const int* __restrict__ csr,
                                                  __hip_bfloat16* __restrict__ aggh)
{
    int b = blockIdx.x & 15;
    int chunk = blockIdx.x >> 4;                    // 0..2499
    int wid = threadIdx.x >> 6;                     // 4 waves = 4 nodes per block
    int n = chunk * 4 + wid;                        // 0..9999
    int w = b * NN + n;
    w = __builtin_amdgcn_readfirstlane(w);          // wave-uniform -> scalar loads
    int lane = threadIdx.x & 63;
    int c = cnt[w];
    int o = off[w];
    const int* row = csr + (size_t)b * NE + o;
    const unsigned short* xb = (const unsigned short*)(xh + (size_t)b * NN * HF);
    float s = 0.f;
    int t = 0;
    for (; t + 4 <= c; t += 4) {
        int i0 = row[t], i1 = row[t+1], i2 = row[t+2], i3 = row[t+3];
        s += __uint_as_float((unsigned)xb[(size_t)i0 * HF + lane] << 16);
        s += __uint_as_float((unsigned)xb[(size_t)i1 * HF + lane] << 16);
        s += __uint_as_float((unsigned)xb[(size_t)i2 * HF + lane] << 16);
        s += __uint_as_float((unsigned)xb[(size_t)i3 * HF + lane] << 16);
    }
    for (; t < c; ++t)
        s += __uint_as_float((unsigned)xb[(size_t)row[t] * HF + lane] << 16);
    float m = (c > 0) ? s / (float)c : 0.f;
    ((unsigned short*)aggh)[(size_t)w * HF + lane] = (unsigned short)(pk_bf16(m, 0.f) & 0xffffu);
}

// ---------------- conv: [x,agg]@W + b, +residual, LN, relu; writes x fp32 + xh bf16 ----------------
__global__ __launch_bounds__(256) void conv_kernel(
    float* __restrict__ x, const __hip_bfloat16* __restrict__ aggh,
    const float* __restrict__ W, const float* __restrict__ bias,
    const float* __restrict__ g, const float* __restrict__ beta,
    __hip_bfloat16* __restrict__ xh)
{
    int node = blockIdx.x * 256 + threadIdx.x;
    const float* xrow = x + (size_t)node * HF;
    const uint4* ap = (const uint4*)(aggh + (size_t)node * HF);   // 8 bf16 per uint4

    float acc[HF];
#pragma unroll
    for (int j = 0; j < HF; ++j) acc[j] = bias[j];

    // agg half: W rows 64..127 (bf16 unpack: lo16<<16, hi16&0xffff0000)
#pragma unroll 1
    for (int kc = 0; kc < HF; kc += 8) {
        uint4 u = ap[kc >> 3];
        float av[8];
        av[0] = __uint_as_float(u.x << 16); av[1] = __uint_as_float(u.x & 0xffff0000u);
        av[2] = __uint_as_float(u.y << 16); av[3] = __uint_as_float(u.y & 0xffff0000u);
        av[4] = __uint_as_float(u.z << 16); av[5] = __uint_as_float(u.z & 0xffff0000u);
        av[6] = __uint_as_float(u.w << 16); av[7] = __uint_as_float(u.w & 0xffff0000u);
#pragma unroll
        for (int uu = 0; uu < 8; ++uu) {
            const float* wr = W + (HF + kc + uu) * HF;
#pragma unroll
            for (int j = 0; j < HF; ++j) acc[j] = fmaf(av[uu], wr[j], acc[j]);
        }
    }

    // x half: W rows 0..63 (fp32 path)
#pragma unroll 1
    for (int kc = 0; kc < HF; kc += 8) {
        float4 v0 = *(const float4*)(xrow + kc);
        float4 v1 = *(const float4*)(xrow + kc + 4);
        float av[8] = {v0.x, v0.y, v0.z, v0.w, v1.x, v1.y, v1.z, v1.w};
#pragma unroll
        for (int uu = 0; uu < 8; ++uu) {
            const float* wr = W + (kc + uu) * HF;
#pragma unroll
            for (int j = 0; j < HF; ++j) acc[j] = fmaf(av[uu], wr[j], acc[j]);
        }
    }

    // residual (reload x row, L1-hit) + LayerNorm + relu
#pragma unroll
    for (int q = 0; q < 16; ++q) {
        float4 r = ((const float4*)xrow)[q];
        acc[4*q]   += r.x; acc[4*q+1] += r.y;
        acc[4*q+2] += r.z; acc[4*q+3] += r.w;
    }
    float mu = 0.f;
#pragma unroll
    for (int j = 0; j < HF; ++j) mu += acc[j];
    mu *= (1.f / HF);
    float var = 0.f;
#pragma unroll
    for (int j = 0; j < HF; ++j) { float d = acc[j] - mu; var += d * d; }
    var *= (1.f / HF);
    float rs = rsqrtf(var + LN_EPS);
#pragma unroll
    for (int j = 0; j < HF; ++j) {
        float y = (acc[j] - mu) * rs * g[j] + beta[j];
        acc[j] = fmaxf(y, 0.f);
    }

    float4* dst = (float4*)(x + (size_t)node * HF);
#pragma unroll
    for (int q = 0; q < 16; ++q) {
        float4 v; v.x = acc[4*q]; v.y = acc[4*q+1]; v.z = acc[4*q+2]; v.w = acc[4*q+3];
        dst[q] = v;
    }
    uint4* hdst = (uint4*)(xh + (size_t)node * HF);
#pragma unroll
    for (int q = 0; q < 8; ++q) {
        uint4 u;
        u.x = pk_bf16(acc[8*q+0], acc[8*q+1]);
        u.y = pk_bf16(acc[8*q+2], acc[8*q+3]);
        u.z = pk_bf16(acc[8*q+4], acc[8*q+5]);
        u.w = pk_bf16(acc[8*q+6], acc[8*q+7]);
        hdst[q] = u;
    }
}

// ---------------- output head: out = x@out_w + out_b ----------------
__global__ __launch_bounds__(256) void out_kernel(const float* __restrict__ x,
                                                  const float* __restrict__ W,
                                                  const float* __restrict__ bias,
                                                  float* __restrict__ out)
{
    int node = blockIdx.x * 256 + threadIdx.x;
    const float* row = x + (size_t)node * HF;

    float o[OUTF];
#pragma unroll
    for (int j = 0; j < OUTF; ++j) o[j] = bias[j];

#pragma unroll 1
    for (int kc = 0; kc < HF; kc += 8) {
        float4 v0 = *(const float4*)(row + kc);
        float4 v1 = *(const float4*)(row + kc + 4);
        float av[8] = {v0.x, v0.y, v0.z, v0.w, v1.x, v1.y, v1.z, v1.w};
#pragma unroll
        for (int u = 0; u < 8; ++u) {
            const float* wr = W + (kc + u) * OUTF;
#pragma unroll
            for (int j = 0; j < OUTF; ++j) o[j] = fmaf(av[u], wr[j], o[j]);
        }
    }

    float4* dst = (float4*)(out + (size_t)node * OUTF);
#pragma unroll
    for (int q = 0; q < 8; ++q) {
        float4 v; v.x = o[4*q]; v.y = o[4*q+1]; v.z = o[4*q+2]; v.w = o[4*q+3];
        dst[q] = v;
    }
}

extern "C" void kernel_launch(void* const* d_in, const int* in_sizes, int n_in,
                              void* d_out, int out_size, void* d_ws, size_t ws_size,
                              hipStream_t stream)
{
    const float* nf     = (const float*)d_in[0];
    const int*   ei     = (const int*)  d_in[1];   // edge_indices (B,2,E)
    const float* enc_w1 = (const float*)d_in[3];
    const float* enc_b1 = (const float*)d_in[4];
    const float* enc_w2 = (const float*)d_in[5];
    const float* enc_b2 = (const float*)d_in[6];
    const float* conv_w = (const float*)d_in[7];   // (3,128,64)
    const float* conv_b = (const float*)d_in[8];   // (3,64)
    const float* ln_g   = (const float*)d_in[9];
    const float* ln_b   = (const float*)d_in[10];
    const float* out_w  = (const float*)d_in[11];  // (64,32)
    const float* out_b  = (const float*)d_in[12];

    // workspace layout (~94 MB)
    char* w = (char*)d_ws;
    float* x            = (float*)w;           w += (size_t)NODES * HF * sizeof(float);  // 41 MB
    __hip_bfloat16* xh  = (__hip_bfloat16*)w;  w += (size_t)NODES * HF * 2;              // 20.5 MB
    __hip_bfloat16* agh = (__hip_bfloat16*)w;  w += (size_t)NODES * HF * 2;              // 20.5 MB
    int* cnt            = (int*)w;             w += (size_t)NODES * sizeof(int);
    int* off            = (int*)w;             w += (size_t)NODES * sizeof(int);
    int* csr            = (int*)w;                                                       // 10.24 MB

    enc1_kernel<<<NODES / 256, 256, 0, stream>>>(nf, enc_w1, enc_b1, x);
    gemm64_kernel<<<NODES / 256, 256, 0, stream>>>(x, enc_w2, enc_b2, xh);
    count_kernel<<<NB * 16, 256, 0, stream>>>(ei, cnt);
    scan_kernel<<<NB, 256, 0, stream>>>(cnt, off);
    fillb_kernel<<<NB * 16, 256, 0, stream>>>(ei, off, csr);

    for (int l = 0; l < 3; ++l) {
        agg_kernel<<<NODES / 4, 256, 0, stream>>>(xh, cnt, off, csr, agh);
        conv_kernel<<<NODES / 256, 256, 0, stream>>>(x, agh,
                                                     conv_w + (size_t)l * 2 * HF * HF,
                                                     conv_b + (size_t)l * HF,
                                                     ln_g + (size_t)l * HF,
                                                     ln_b + (size_t)l * HF,
                                                     xh);
    }
    out_kernel<<<NODES / 256, 256, 0, stream>>>(x, out_w, out_b, (float*)d_out);
}

// Round 6
// 604.355 us; speedup vs baseline: 1.9403x; 1.9403x over previous
//
#include <hip/hip_runtime.h>
#include <hip/hip_bf16.h>

#define NB   16       // batches
#define NN   10000    // nodes per batch
#define NE   160000   // edges per batch
#define NODES (NB*NN) // 160000 total nodes
#define IN_F 19
#define HF   64
#define OUTF 32
#define LN_EPS 1e-5f
#define RANGE 625     // dst nodes per bucket (16 buckets/batch)
#define NCHUNK 32     // edge chunks per batch in bucket_kernel
#define CHSZ (NE/NCHUNK)   // 5000 edges per chunk
#define BCAP 16384    // bucket capacity (entries); mean 10000, sigma ~97

// R6 structure notes:
// * CSR line-ownership is required (R4: edge-scatter fill wrote 117MB HBM for
//   10.2MB of CSR -- same-line stores from different XCDs never merge), but
//   R5's monolithic owner blocks killed parallelism (256 blocks re-reading
//   the whole dst stream 16x, 378us). Fix: two-level binning. bucket_kernel
//   (512 blocks) bins edge chunks into per-(batch,range) global buckets with
//   16 LDS counters + 1 global atomic per bucket per block; count2/fill2 then
//   read ONLY their own bucket (~40KB) and write an exclusively-owned
//   contiguous CSR segment -> full-line writebacks.
// * bucket storage aliases agh (agg written only after fill2 done).
// * agg/gathers in bf16 (xh shadow) -> gather bytes halved; fp32 x kept for
//   dense math + residual + LN. Dense kernels: chunk k by 8, constant-indexed
//   av[8], wave-uniform weight rows -> s_load + v_fmac(SGPR). No spills.

__device__ inline unsigned pk_bf16(float a, float b) {
    __hip_bfloat162 h = __float22bfloat162_rn(float2{a, b});
    return *(unsigned*)&h;
}

// ---------------- enc1: h = relu(nf@W1+b1), fully unrolled (k=19 const) ----------------
__global__ __launch_bounds__(256) void enc1_kernel(
    const float* __restrict__ nf,
    const float* __restrict__ w1, const float* __restrict__ b1,
    float* __restrict__ x)
{
    int node = blockIdx.x * 256 + threadIdx.x;   // 625*256 = 160000 exactly
    const float* p = nf + (size_t)node * IN_F;
    float a[IN_F];
#pragma unroll
    for (int k = 0; k < IN_F; ++k) a[k] = p[k];

    float h[HF];
#pragma unroll
    for (int j = 0; j < HF; ++j) h[j] = b1[j];
#pragma unroll
    for (int k = 0; k < IN_F; ++k) {
        float ak = a[k];
        const float* wr = w1 + k * HF;           // wave-uniform -> s_load
#pragma unroll
        for (int j = 0; j < HF; ++j) h[j] = fmaf(ak, wr[j], h[j]);
    }

    float4* dst = (float4*)(x + (size_t)node * HF);
#pragma unroll
    for (int q = 0; q < 16; ++q) {
        float4 v;
        v.x = fmaxf(h[4*q],   0.f); v.y = fmaxf(h[4*q+1], 0.f);
        v.z = fmaxf(h[4*q+2], 0.f); v.w = fmaxf(h[4*q+3], 0.f);
        dst[q] = v;
    }
}

// ---------------- gemm64: x = x @ W + b in-place; also writes bf16 shadow xh ----------------
__global__ __launch_bounds__(256) void gemm64_kernel(
    float* __restrict__ x, const float* __restrict__ W, const float* __restrict__ bias,
    __hip_bfloat16* __restrict__ xh)
{
    int node = blockIdx.x * 256 + threadIdx.x;
    const float* row = x + (size_t)node * HF;

    float acc[HF];
#pragma unroll
    for (int j = 0; j < HF; ++j) acc[j] = bias[j];

#pragma unroll 1
    for (int kc = 0; kc < HF; kc += 8) {
        float4 v0 = *(const float4*)(row + kc);
        float4 v1 = *(const float4*)(row + kc + 4);
        float av[8] = {v0.x, v0.y, v0.z, v0.w, v1.x, v1.y, v1.z, v1.w};
#pragma unroll
        for (int u = 0; u < 8; ++u) {
            const float* wr = W + (kc + u) * HF;
#pragma unroll
            for (int j = 0; j < HF; ++j) acc[j] = fmaf(av[u], wr[j], acc[j]);
        }
    }

    float4* dst = (float4*)(x + (size_t)node * HF);
#pragma unroll
    for (int q = 0; q < 16; ++q) {
        float4 v; v.x = acc[4*q]; v.y = acc[4*q+1]; v.z = acc[4*q+2]; v.w = acc[4*q+3];
        dst[q] = v;
    }
    uint4* hdst = (uint4*)(xh + (size_t)node * HF);
#pragma unroll
    for (int q = 0; q < 8; ++q) {
        uint4 u;
        u.x = pk_bf16(acc[8*q+0], acc[8*q+1]);
        u.y = pk_bf16(acc[8*q+2], acc[8*q+3]);
        u.z = pk_bf16(acc[8*q+4], acc[8*q+5]);
        u.w = pk_bf16(acc[8*q+6], acc[8*q+7]);
        hdst[q] = u;
    }
}

// ---------------- bucket: bin edge chunks into per-(batch,range) buckets ----------------
__global__ __launch_bounds__(256) void bucket_kernel(const int* __restrict__ ei,
                                                     int* __restrict__ gcur,
                                                     unsigned* __restrict__ bkt)
{
    __shared__ int lcnt[16];
    __shared__ int lcur[16];
    __shared__ int gbase[16];
    int b = blockIdx.x >> 5;                     // NCHUNK=32 chunks per batch
    int chunk = blockIdx.x & 31;
    int t = threadIdx.x;
    if (t < 16) { lcnt[t] = 0; lcur[t] = 0; }
    __syncthreads();

    const int* srcp = ei + (size_t)b * 2 * NE + chunk * CHSZ;
    const int* dstp = srcp + NE;

    for (int e = t; e < CHSZ; e += 256)
        atomicAdd(&lcnt[(unsigned)dstp[e] / RANGE], 1);
    __syncthreads();
    if (t < 16) gbase[t] = atomicAdd(&gcur[b * 16 + t], lcnt[t]);
    __syncthreads();

    for (int e = t; e < CHSZ; e += 256) {
        int d = dstp[e];                          // L1-hot (2nd pass)
        int s = srcp[e];
        int j = (unsigned)d / RANGE;
        int ld = d - j * RANGE;
        int pos = gbase[j] + atomicAdd(&lcur[j], 1);
        if (pos < BCAP)
            bkt[(size_t)(b * 16 + j) * BCAP + pos] = (unsigned)s | ((unsigned)ld << 16);
    }
}

// ---------------- count2: per-bucket histogram -> cnt ----------------
__global__ __launch_bounds__(512) void count2_kernel(const unsigned* __restrict__ bkt,
                                                     const int* __restrict__ gcur,
                                                     int* __restrict__ cnt)
{
    __shared__ int lcnt[RANGE];
    int bid = blockIdx.x;                        // b*16 + j
    int b = bid >> 4, j = bid & 15;
    int t = threadIdx.x;
    for (int i = t; i < RANGE; i += 512) lcnt[i] = 0;
    __syncthreads();
    int n = min(gcur[bid], BCAP);
    const unsigned* bp = bkt + (size_t)bid * BCAP;
    for (int e = t; e < n; e += 512) atomicAdd(&lcnt[bp[e] >> 16], 1);
    __syncthreads();
    int base = b * NN + j * RANGE;
    for (int i = t; i < RANGE; i += 512) cnt[base + i] = lcnt[i];
}

// ---------------- scan: per-batch exclusive prefix over cnt ----------------
__global__ __launch_bounds__(256) void scan_kernel(const int* __restrict__ cnt, int* __restrict__ off)
{
    __shared__ int sdata[256];
    int b = blockIdx.x, t = threadIdx.x;
    const int CH = 40;                          // 256*40 = 10240 >= NN
    int lo = t * CH, hi = min(lo + CH, NN);
    int s = 0;
    for (int i = lo; i < hi; ++i) s += cnt[b * NN + i];
    sdata[t] = s;
    __syncthreads();
    for (int ofs = 1; ofs < 256; ofs <<= 1) {
        int v = (t >= ofs) ? sdata[t - ofs] : 0;
        __syncthreads();
        sdata[t] += v;
        __syncthreads();
    }
    int run = (t > 0) ? sdata[t - 1] : 0;       // exclusive prefix
    for (int i = lo; i < hi; ++i) { off[b * NN + i] = run; run += cnt[b * NN + i]; }
}

// ---------------- fill2: per-bucket fill of the block-owned CSR segment ----------------
__global__ __launch_bounds__(512) void fill2_kernel(const unsigned* __restrict__ bkt,
                                                    const int* __restrict__ gcur,
                                                    const int* __restrict__ off,
                                                    int* __restrict__ csr)
{
    __shared__ int lcur[RANGE];
    int bid = blockIdx.x;                        // b*16 + j
    int b = bid >> 4, j = bid & 15;
    int t = threadIdx.x;
    for (int i = t; i < RANGE; i += 512) lcur[i] = 0;
    __syncthreads();
    int n = min(gcur[bid], BCAP);
    const unsigned* bp = bkt + (size_t)bid * BCAP;
    const int* offb = off + b * NN + j * RANGE;
    int* csrb = csr + (size_t)b * NE;
    for (int e = t; e < n; e += 512) {
        unsigned u = bp[e];
        int ld = u >> 16;
        int pos = offb[ld] + atomicAdd(&lcur[ld], 1);
        csrb[pos] = (int)(u & 0xffffu);          // block-exclusive ~40KB segment
    }
}

// ---------------- mean aggregation: wave per node, lane per channel, bf16 gathers ----------------
__global__ __launch_bounds__(256) void agg_kernel(const __hip_bfloat16* __restrict__ xh,
                                                  const int* __restrict__ cnt,
                                                  const int* __restrict__ off,
                                                  const int* __restrict__ csr,
                                                  __hip_bfloat16* __restrict__ aggh)
{
    int b = blockIdx.x & 15;
    int chunk = blockIdx.x >> 4;                    // 0..2499
    int wid = threadIdx.x >> 6;                     // 4 waves = 4 nodes per block
    int n = chunk * 4 + wid;                        // 0..9999
    int w = b * NN + n;
    w = __builtin_amdgcn_readfirstlane(w);          // wave-uniform -> scalar loads
    int lane = threadIdx.x & 63;
    int c = cnt[w];
    int o = off[w];
    const int* row = csr + (size_t)b * NE + o;
    const unsigned short* xb = (const unsigned short*)(xh + (size_t)b * NN * HF);
    float s = 0.f;
    int t = 0;
    for (; t + 4 <= c; t += 4) {
        int i0 = row[t], i1 = row[t+1], i2 = row[t+2], i3 = row[t+3];
        s += __uint_as_float((unsigned)xb[(size_t)i0 * HF + lane] << 16);
        s += __uint_as_float((unsigned)xb[(size_t)i1 * HF + lane] << 16);
        s += __uint_as_float((unsigned)xb[(size_t)i2 * HF + lane] << 16);
        s += __uint_as_float((unsigned)xb[(size_t)i3 * HF + lane] << 16);
    }
    for (; t < c; ++t)
        s += __uint_as_float((unsigned)xb[(size_t)row[t] * HF + lane] << 16);
    float m = (c > 0) ? s / (float)c : 0.f;
    ((unsigned short*)aggh)[(size_t)w * HF + lane] = (unsigned short)(pk_bf16(m, 0.f) & 0xffffu);
}

// ---------------- conv: [x,agg]@W + b, +residual, LN, relu; writes x fp32 + xh bf16 ----------------
__global__ __launch_bounds__(256) void conv_kernel(
    float* __restrict__ x, const __hip_bfloat16* __restrict__ aggh,
    const float* __restrict__ W, const float* __restrict__ bias,
    const float* __restrict__ g, const float* __restrict__ beta,
    __hip_bfloat16* __restrict__ xh)
{
    int node = blockIdx.x * 256 + threadIdx.x;
    const float* xrow = x + (size_t)node * HF;
    const uint4* ap = (const uint4*)(aggh + (size_t)node * HF);   // 8 bf16 per uint4

    float acc[HF];
#pragma unroll
    for (int j = 0; j < HF; ++j) acc[j] = bias[j];

    // agg half: W rows 64..127 (bf16 unpack: lo16<<16, hi16&0xffff0000)
#pragma unroll 1
    for (int kc = 0; kc < HF; kc += 8) {
        uint4 u = ap[kc >> 3];
        float av[8];
        av[0] = __uint_as_float(u.x << 16); av[1] = __uint_as_float(u.x & 0xffff0000u);
        av[2] = __uint_as_float(u.y << 16); av[3] = __uint_as_float(u.y & 0xffff0000u);
        av[4] = __uint_as_float(u.z << 16); av[5] = __uint_as_float(u.z & 0xffff0000u);
        av[6] = __uint_as_float(u.w << 16); av[7] = __uint_as_float(u.w & 0xffff0000u);
#pragma unroll
        for (int uu = 0; uu < 8; ++uu) {
            const float* wr = W + (HF + kc + uu) * HF;
#pragma unroll
            for (int j = 0; j < HF; ++j) acc[j] = fmaf(av[uu], wr[j], acc[j]);
        }
    }

    // x half: W rows 0..63 (fp32 path)
#pragma unroll 1
    for (int kc = 0; kc < HF; kc += 8) {
        float4 v0 = *(const float4*)(xrow + kc);
        float4 v1 = *(const float4*)(xrow + kc + 4);
        float av[8] = {v0.x, v0.y, v0.z, v0.w, v1.x, v1.y, v1.z, v1.w};
#pragma unroll
        for (int uu = 0; uu < 8; ++uu) {
            const float* wr = W + (kc + uu) * HF;
#pragma unroll
            for (int j = 0; j < HF; ++j) acc[j] = fmaf(av[uu], wr[j], acc[j]);
        }
    }

    // residual (reload x row, L1-hit) + LayerNorm + relu
#pragma unroll
    for (int q = 0; q < 16; ++q) {
        float4 r = ((const float4*)xrow)[q];
        acc[4*q]   += r.x; acc[4*q+1] += r.y;
        acc[4*q+2] += r.z; acc[4*q+3] += r.w;
    }
    float mu = 0.f;
#pragma unroll
    for (int j = 0; j < HF; ++j) mu += acc[j];
    mu *= (1.f / HF);
    float var = 0.f;
#pragma unroll
    for (int j = 0; j < HF; ++j) { float d = acc[j] - mu; var += d * d; }
    var *= (1.f / HF);
    float rs = rsqrtf(var + LN_EPS);
#pragma unroll
    for (int j = 0; j < HF; ++j) {
        float y = (acc[j] - mu) * rs * g[j] + beta[j];
        acc[j] = fmaxf(y, 0.f);
    }

    float4* dst = (float4*)(x + (size_t)node * HF);
#pragma unroll
    for (int q = 0; q < 16; ++q) {
        float4 v; v.x = acc[4*q]; v.y = acc[4*q+1]; v.z = acc[4*q+2]; v.w = acc[4*q+3];
        dst[q] = v;
    }
    uint4* hdst = (uint4*)(xh + (size_t)node * HF);
#pragma unroll
    for (int q = 0; q < 8; ++q) {
        uint4 u;
        u.x = pk_bf16(acc[8*q+0], acc[8*q+1]);
        u.y = pk_bf16(acc[8*q+2], acc[8*q+3]);
        u.z = pk_bf16(acc[8*q+4], acc[8*q+5]);
        u.w = pk_bf16(acc[8*q+6], acc[8*q+7]);
        hdst[q] = u;
    }
}

// ---------------- output head: out = x@out_w + out_b ----------------
__global__ __launch_bounds__(256) void out_kernel(const float* __restrict__ x,
                                                  const float* __restrict__ W,
                                                  const float* __restrict__ bias,
                                                  float* __restrict__ out)
{
    int node = blockIdx.x * 256 + threadIdx.x;
    const float* row = x + (size_t)node * HF;

    float o[OUTF];
#pragma unroll
    for (int j = 0; j < OUTF; ++j) o[j] = bias[j];

#pragma unroll 1
    for (int kc = 0; kc < HF; kc += 8) {
        float4 v0 = *(const float4*)(row + kc);
        float4 v1 = *(const float4*)(row + kc + 4);
        float av[8] = {v0.x, v0.y, v0.z, v0.w, v1.x, v1.y, v1.z, v1.w};
#pragma unroll
        for (int u = 0; u < 8; ++u) {
            const float* wr = W + (kc + u) * OUTF;
#pragma unroll
            for (int j = 0; j < OUTF; ++j) o[j] = fmaf(av[u], wr[j], o[j]);
        }
    }

    float4* dst = (float4*)(out + (size_t)node * OUTF);
#pragma unroll
    for (int q = 0; q < 8; ++q) {
        float4 v; v.x = o[4*q]; v.y = o[4*q+1]; v.z = o[4*q+2]; v.w = o[4*q+3];
        dst[q] = v;
    }
}

extern "C" void kernel_launch(void* const* d_in, const int* in_sizes, int n_in,
                              void* d_out, int out_size, void* d_ws, size_t ws_size,
                              hipStream_t stream)
{
    const float* nf     = (const float*)d_in[0];
    const int*   ei     = (const int*)  d_in[1];   // edge_indices (B,2,E)
    const float* enc_w1 = (const float*)d_in[3];
    const float* enc_b1 = (const float*)d_in[4];
    const float* enc_w2 = (const float*)d_in[5];
    const float* enc_b2 = (const float*)d_in[6];
    const float* conv_w = (const float*)d_in[7];   // (3,128,64)
    const float* conv_b = (const float*)d_in[8];   // (3,64)
    const float* ln_g   = (const float*)d_in[9];
    const float* ln_b   = (const float*)d_in[10];
    const float* out_w  = (const float*)d_in[11];  // (64,32)
    const float* out_b  = (const float*)d_in[12];

    // workspace layout (~94 MB); bkt aliases agh (bucket data dead once fill2 runs)
    char* w = (char*)d_ws;
    float* x            = (float*)w;           w += (size_t)NODES * HF * sizeof(float);  // 41 MB
    __hip_bfloat16* xh  = (__hip_bfloat16*)w;  w += (size_t)NODES * HF * 2;              // 20.5 MB
    __hip_bfloat16* agh = (__hip_bfloat16*)w;  w += (size_t)NODES * HF * 2;              // 20.5 MB
    unsigned* bkt       = (unsigned*)agh;      // 256 buckets * 16384 * 4B = 16.8 MB ≤ 20.5 MB
    int* cnt            = (int*)w;             w += (size_t)NODES * sizeof(int);
    int* off            = (int*)w;             w += (size_t)NODES * sizeof(int);
    int* csr            = (int*)w;             w += (size_t)NB * NE * sizeof(int);       // 10.24 MB
    int* gcur           = (int*)w;                                                       // 256 ints

    hipMemsetAsync(gcur, 0, 256 * sizeof(int), stream);

    enc1_kernel<<<NODES / 256, 256, 0, stream>>>(nf, enc_w1, enc_b1, x);
    gemm64_kernel<<<NODES / 256, 256, 0, stream>>>(x, enc_w2, enc_b2, xh);
    bucket_kernel<<<NB * NCHUNK, 256, 0, stream>>>(ei, gcur, bkt);
    count2_kernel<<<NB * 16, 512, 0, stream>>>(bkt, gcur, cnt);
    scan_kernel<<<NB, 256, 0, stream>>>(cnt, off);
    fill2_kernel<<<NB * 16, 512, 0, stream>>>(bkt, gcur, off, csr);

    for (int l = 0; l < 3; ++l) {
        agg_kernel<<<NODES / 4, 256, 0, stream>>>(xh, cnt, off, csr, agh);
        conv_kernel<<<NODES / 256, 256, 0, stream>>>(x, agh,
                                                     conv_w + (size_t)l * 2 * HF * HF,
                                                     conv_b + (size_t)l * HF,
                                                     ln_g + (size_t)l * HF,
                                                     ln_b + (size_t)l * HF,
                                                     xh);
    }
    out_kernel<<<NODES / 256, 256, 0, stream>>>(x, out_w, out_b, (float*)d_out);
}